// Round 1
// baseline (164.192 us; speedup 1.0000x reference)
//
#include <hip/hip_runtime.h>

constexpr int BLOCK = 256;
constexpr int CHUNK = 2048;   // points staged in LDS per pass (2048 * 16B = 32 KiB)

// One thread = one query point. Both chamfer directions share one grid:
// blocks [0, B*N/BLOCK) do rec->data, the rest do data->rec.
__global__ __launch_bounds__(BLOCK)
void chamfer_nn_kernel(const float* __restrict__ rec,
                       const float* __restrict__ data,
                       float* __restrict__ block_sums,
                       int N, int M, int B)
{
    __shared__ float4 pts[CHUNK];
    __shared__ float wsum[BLOCK / 64];

    const int nb0  = N / BLOCK;            // blocks per batch, dir 0
    const int bpd0 = B * nb0;              // total blocks dir 0
    const bool dir1 = (int)blockIdx.x >= bpd0;
    const int  lb   = dir1 ? (int)blockIdx.x - bpd0 : (int)blockIdx.x;

    const float* __restrict__ qbase = dir1 ? data : rec;
    const float* __restrict__ pbase = dir1 ? rec  : data;
    const int Nq = dir1 ? M : N;
    const int Np = dir1 ? N : M;

    const int nbq = Nq / BLOCK;
    const int b   = lb / nbq;
    const int qi  = (lb % nbq) * BLOCK + threadIdx.x;

    const float* qp = qbase + ((size_t)b * Nq + qi) * 3;
    const float qx = qp[0], qy = qp[1], qz = qp[2];
    const float* pb = pbase + (size_t)b * Np * 3;

    // 8 independent min accumulators for ILP (1 wave/SIMD at this grid size)
    float m0 = 3.4e38f, m1 = 3.4e38f, m2 = 3.4e38f, m3 = 3.4e38f;
    float m4 = 3.4e38f, m5 = 3.4e38f, m6 = 3.4e38f, m7 = 3.4e38f;

    for (int base = 0; base < Np; base += CHUNK) {
        __syncthreads();   // previous chunk's compute done before overwrite
        for (int j = threadIdx.x; j < CHUNK; j += BLOCK) {
            const float* pp = pb + (size_t)(base + j) * 3;
            pts[j] = make_float4(pp[0], pp[1], pp[2], 0.0f);
        }
        __syncthreads();

#define DIST(K, ACC) { float4 p = pts[j + (K)];                         \
        float dx = qx - p.x, dy = qy - p.y, dz = qz - p.z;              \
        float d = fmaf(dz, dz, fmaf(dy, dy, dx * dx));                  \
        ACC = fminf(ACC, d); }

        #pragma unroll 2
        for (int j = 0; j < CHUNK; j += 8) {
            DIST(0, m0) DIST(1, m1) DIST(2, m2) DIST(3, m3)
            DIST(4, m4) DIST(5, m5) DIST(6, m6) DIST(7, m7)
        }
#undef DIST
    }

    float m = fminf(fminf(fminf(m0, m1), fminf(m2, m3)),
                    fminf(fminf(m4, m5), fminf(m6, m7)));
    // direct (x-y)^2 formula is >= 0 already (matches ref's maximum(d, 0))

    // per-query min -> block sum (deterministic: shuffle + LDS, no atomics)
    for (int off = 32; off; off >>= 1) m += __shfl_down(m, off);
    if ((threadIdx.x & 63) == 0) wsum[threadIdx.x >> 6] = m;
    __syncthreads();
    if (threadIdx.x == 0) {
        float s = 0.f;
        for (int w = 0; w < BLOCK / 64; ++w) s += wsum[w];
        block_sums[blockIdx.x] = s;
    }
}

// Combine per-block sums: mean_b( max(sum_rec/N, sum_data/M) )
__global__ __launch_bounds__(256)
void chamfer_finalize(const float* __restrict__ bs, float* __restrict__ out,
                      int nb0, int nb1, int B, int N, int M)
{
    __shared__ float seg[16];
    const int tid  = threadIdx.x;
    const int nseg = 2 * B;
    if (tid < nseg * 32) {
        const int s = tid / 32, l = tid % 32;
        const int dir = s / B, b = s % B;
        const int cnt = dir ? nb1 : nb0;
        const float* p = bs + (dir ? B * nb0 + b * nb1 : b * nb0);
        float v = 0.f;
        for (int i = l; i < cnt; i += 32) v += p[i];
        for (int off = 16; off; off >>= 1) v += __shfl_down(v, off, 32);
        if (l == 0) seg[s] = v;
    }
    __syncthreads();
    if (tid == 0) {
        float acc = 0.f;
        for (int b = 0; b < B; ++b)
            acc += fmaxf(seg[b] / (float)N, seg[B + b] / (float)M);
        out[0] = acc / (float)B;
    }
}

extern "C" void kernel_launch(void* const* d_in, const int* in_sizes, int n_in,
                              void* d_out, int out_size, void* d_ws, size_t ws_size,
                              hipStream_t stream)
{
    const float* rec  = (const float*)d_in[0];
    const float* data = (const float*)d_in[1];
    const int B = 4;
    const int N = in_sizes[0] / (B * 3);
    const int M = in_sizes[1] / (B * 3);

    float* bs = (float*)d_ws;                 // (B*nb0 + B*nb1) floats
    const int nb0 = N / BLOCK, nb1 = M / BLOCK;
    const int grid = B * (nb0 + nb1);         // 256 blocks for 4x8192/8192

    chamfer_nn_kernel<<<grid, BLOCK, 0, stream>>>(rec, data, bs, N, M, B);
    chamfer_finalize<<<1, 256, 0, stream>>>(bs, (float*)d_out, nb0, nb1, B, N, M);
}

// Round 2
// 56.099 us; speedup vs baseline: 2.9268x; 2.9268x over previous
//
#include <hip/hip_runtime.h>

constexpr int BLOCK = 256;
constexpr int QPT   = 8;              // queries per thread (register tile)
constexpr int QPB   = BLOCK * QPT;    // 2048 queries per block

// Stage 1: partial per-query min over one point-slice.
// Points pre-transformed in LDS to (-2px, -2py, -2pz, |p|^2) so each
// distance (minus the deferred |q|^2 term) is 3 fma + 1 min.
__global__ __launch_bounds__(BLOCK)
void chamfer_partial_kernel(const float* __restrict__ rec,
                            const float* __restrict__ data,
                            float* __restrict__ partial,   // [S][TOTQ]
                            int N, int M, int B, int S)
{
    extern __shared__ float4 pts[];    // slice points, transformed

    const int bid = blockIdx.x;
    const int qb  = bid / S;           // query-block index
    const int s   = bid % S;           // point-slice index
    const int q0  = qb * QPB;
    const int TOTQ0 = B * N;
    const int TOTQ  = B * (N + M);

    const bool dir1 = q0 >= TOTQ0;
    const int  lq0  = dir1 ? q0 - TOTQ0 : q0;
    const int  Nq   = dir1 ? M : N;
    const int  Np   = dir1 ? N : M;
    const int  b    = lq0 / Nq;

    const float* __restrict__ qbase =
        (dir1 ? data : rec) + ((size_t)b * Nq + (lq0 % Nq)) * 3;
    const float* __restrict__ pbase =
        (dir1 ? rec : data) + (size_t)b * Np * 3;

    const int slice = Np / S;
    const int p0    = s * slice;

    for (int j = threadIdx.x; j < slice; j += BLOCK) {
        const float* pp = pbase + (size_t)(p0 + j) * 3;
        const float px = pp[0], py = pp[1], pz = pp[2];
        pts[j] = make_float4(-2.f * px, -2.f * py, -2.f * pz,
                             fmaf(px, px, fmaf(py, py, pz * pz)));
    }
    __syncthreads();

    float qx[QPT], qy[QPT], qz[QPT], mn[QPT];
    #pragma unroll
    for (int k = 0; k < QPT; ++k) {
        const float* qp = qbase + (size_t)(k * BLOCK + threadIdx.x) * 3;
        qx[k] = qp[0]; qy[k] = qp[1]; qz[k] = qp[2];
        mn[k] = 3.4e38f;
    }

    #pragma unroll 4
    for (int j = 0; j < slice; ++j) {
        const float4 p = pts[j];
        #pragma unroll
        for (int k = 0; k < QPT; ++k) {
            float t = fmaf(qz[k], p.z, p.w);
            t       = fmaf(qy[k], p.y, t);
            t       = fmaf(qx[k], p.x, t);
            mn[k]   = fminf(mn[k], t);
        }
    }

    float* out = partial + (size_t)s * TOTQ + q0;
    #pragma unroll
    for (int k = 0; k < QPT; ++k)
        out[k * BLOCK + threadIdx.x] = mn[k];
}

// Stage 2: per query, min across S slices, add |q|^2, clamp, block-sum.
__global__ __launch_bounds__(BLOCK)
void chamfer_reduce_kernel(const float* __restrict__ rec,
                           const float* __restrict__ data,
                           const float* __restrict__ partial,
                           float* __restrict__ block_sums,
                           int N, int M, int B, int S)
{
    __shared__ float wsum[BLOCK / 64];
    const int q = blockIdx.x * BLOCK + threadIdx.x;
    const int TOTQ0 = B * N;
    const int TOTQ  = B * (N + M);

    float mn = 3.4e38f;
    for (int s = 0; s < S; ++s)
        mn = fminf(mn, partial[(size_t)s * TOTQ + q]);

    const bool dir1 = q >= TOTQ0;
    const int  lq   = dir1 ? q - TOTQ0 : q;
    const float* qp = (dir1 ? data : rec) + (size_t)lq * 3;
    const float q2  = fmaf(qp[0], qp[0], fmaf(qp[1], qp[1], qp[2] * qp[2]));
    float d = fmaxf(mn + q2, 0.0f);

    for (int off = 32; off; off >>= 1) d += __shfl_down(d, off);
    if ((threadIdx.x & 63) == 0) wsum[threadIdx.x >> 6] = d;
    __syncthreads();
    if (threadIdx.x == 0) {
        float ssum = 0.f;
        for (int w = 0; w < BLOCK / 64; ++w) ssum += wsum[w];
        block_sums[blockIdx.x] = ssum;
    }
}

// Finalize: mean_b( max(sum_rec/N, sum_data/M) )
__global__ __launch_bounds__(256)
void chamfer_finalize(const float* __restrict__ bs, float* __restrict__ out,
                      int N, int M, int B)
{
    __shared__ float smem[256];
    __shared__ float seg[16];
    const int nb0 = N / BLOCK, nb1 = M / BLOCK;
    const int nblk = B * (nb0 + nb1);
    const int tid = threadIdx.x;
    smem[tid] = (tid < nblk) ? bs[tid] : 0.f;
    __syncthreads();
    if (tid < 2 * B) {
        const int dir = tid / B, b = tid % B;
        const int cnt = dir ? nb1 : nb0;
        const int off = dir ? B * nb0 + b * nb1 : b * nb0;
        float v = 0.f;
        for (int i = 0; i < cnt; ++i) v += smem[off + i];
        seg[tid] = v;
    }
    __syncthreads();
    if (tid == 0) {
        float acc = 0.f;
        for (int b = 0; b < B; ++b)
            acc += fmaxf(seg[b] / (float)N, seg[B + b] / (float)M);
        out[0] = acc / (float)B;
    }
}

extern "C" void kernel_launch(void* const* d_in, const int* in_sizes, int n_in,
                              void* d_out, int out_size, void* d_ws, size_t ws_size,
                              hipStream_t stream)
{
    const float* rec  = (const float*)d_in[0];
    const float* data = (const float*)d_in[1];
    const int B = 4;
    const int N = in_sizes[0] / (B * 3);
    const int M = in_sizes[1] / (B * 3);
    const int TOTQ = B * (N + M);

    // Pick largest point-split S (power of 2) whose partial array fits d_ws.
    int S = 32;
    const int nblk2 = TOTQ / BLOCK;                    // stage-2 blocks
    while (S > 1 &&
           (size_t)S * TOTQ * sizeof(float) + (size_t)nblk2 * sizeof(float) > ws_size)
        S >>= 1;

    float* partial    = (float*)d_ws;                  // [S][TOTQ]
    float* block_sums = partial + (size_t)S * TOTQ;    // [nblk2]

    const int grid1   = (TOTQ / QPB) * S;
    const int maxNp   = (N > M) ? N : M;
    const size_t lds1 = (size_t)(maxNp / S) * sizeof(float4);

    chamfer_partial_kernel<<<grid1, BLOCK, lds1, stream>>>(rec, data, partial,
                                                           N, M, B, S);
    chamfer_reduce_kernel<<<nblk2, BLOCK, 0, stream>>>(rec, data, partial,
                                                       block_sums, N, M, B, S);
    chamfer_finalize<<<1, 256, 0, stream>>>(block_sums, (float*)d_out, N, M, B);
}